// Round 7
// baseline (138.048 us; speedup 1.0000x reference)
//
#include <hip/hip_runtime.h>
#include <cstdint>
#include <cstddef>

#define EPSC 1e-7f
#define EPS9 1e-9f
#define K4PI2 0.40528473456935108577f
#define NTOPK 10
#define SEG 512              // per-wave LDS segment capacity (4 waves -> 2048 total)

__device__ __forceinline__ bool better(float v1, int i1, float v2, int i2) {
    return (v1 > v2) || ((v1 == v2) && (i1 < i2));
}

// mask accessor: wide (int32/float32 0-or-1) vs byte (uint8) layout
__device__ __forceinline__ bool mask_at(const unsigned char* mb, int i, int wide) {
    if (wide) return reinterpret_cast<const unsigned int*>(mb)[i] != 0u;
    return mb[i] != 0;
}

__device__ __forceinline__ unsigned long long shfl_xor_u64(unsigned long long v, int off) {
    int lo = __shfl_xor((int)(unsigned)(v & 0xFFFFFFFFull), off);
    int hi = __shfl_xor((int)(unsigned)(v >> 32), off);
    return ((unsigned long long)(unsigned)hi << 32) | (unsigned)lo;
}

__device__ __forceinline__ unsigned lane_rank(unsigned long long ball) {
    return __builtin_amdgcn_mbcnt_hi((unsigned)(ball >> 32),
           __builtin_amdgcn_mbcnt_lo((unsigned)(ball & 0xFFFFFFFFull), 0u));
}

// flattened candidate index g -> LDS slot (4 segments, branchless selects)
__device__ __forceinline__ int seg_slot(int g, int o1, int o2, int o3) {
    int w = (g >= o1) + (g >= o2) + (g >= o3);
    int off = (w == 0) ? 0 : (w == 1 ? o1 : (w == 2 ? o2 : o3));
    return w * SEG + (g - off);
}

// valid-masked, clipped CIoU between gt (precomputed w1h1, atan1) and pred box pb
__device__ __forceinline__ float ciou_clip(float x1a, float y1a, float x2a, float y2a,
                                           float w1h1, float atan1,
                                           float4 pb, float at2) {
    float w2 = pb.z - pb.x, h2 = pb.w - pb.y + EPSC;
    float iw = fmaxf(fminf(x2a, pb.z) - fmaxf(x1a, pb.x), 0.f);
    float ih = fmaxf(fminf(y2a, pb.w) - fmaxf(y1a, pb.y), 0.f);
    float inter = iw * ih;
    float uni = w1h1 + w2 * h2 - inter;
    float iou = inter / (uni + EPSC);
    float cw = fmaxf(x2a, pb.z) - fminf(x1a, pb.x);
    float ch = fmaxf(y2a, pb.w) - fminf(y1a, pb.y);
    float c2 = cw * cw + ch * ch + EPSC;
    float dx = pb.x + pb.z - x1a - x2a;
    float dy = pb.y + pb.w - y1a - y2a;
    float rho2 = (dx * dx + dy * dy) * 0.25f;
    float dat = at2 - atan1;
    float vv = K4PI2 * dat * dat;
    float aa = vv / (vv - iou + (1.f + EPSC));
    return fmaxf(iou - (rho2 / c2 + vv * aa), 0.f);
}

// K0: detect mask_gt memory layout. wide iff all n/4 leading words are {0,1,1.0f}
__global__ void k_detect(const unsigned char* __restrict__ mask, int n, int* __restrict__ mode) {
    __shared__ int bad;
    if (threadIdx.x == 0) bad = 0;
    __syncthreads();
    const unsigned int* w = reinterpret_cast<const unsigned int*>(mask);
    int nw = n >> 2;
    for (int i = threadIdx.x; i < nw; i += 256) {
        unsigned int v = w[i];
        if (v != 0u && v != 1u && v != 0x3f800000u) atomicOr(&bad, 1);
    }
    __syncthreads();
    if (threadIdx.x == 0) mode[0] = bad ? 0 : 1;
}

// Shared body. PH=1: phase-1 scan/compact only (keepalive to scr). PH=2: +metric compute.
// PH=3: full (real pipeline).
template<int PH>
__device__ __forceinline__ void topk_body(
    const float* __restrict__ pd_scores, const float* __restrict__ pd_bboxes,
    const float* __restrict__ anc, const float* __restrict__ gt_labels,
    const float* __restrict__ gt_bboxes, const unsigned char* __restrict__ mask_gt,
    const int* __restrict__ mode,
    int* __restrict__ count, int* __restrict__ win_idx, float* __restrict__ win_al,
    int* __restrict__ win_fl, int* __restrict__ ovf, int* __restrict__ scr,
    int A, int C, int M, int B)
{
    __shared__ unsigned long long keys[4 * SEG];
    __shared__ int s_cnt[4];
    __shared__ int s_p;

    int bid = blockIdx.x;
    int b = bid % B;                 // XCD swizzle: all blocks of batch b share an XCD L2
    int m = bid / B;
    int row = b * M + m;             // row-major (b,m) index for gt/win arrays
    int tid = threadIdx.x;
    int lane = tid & 63, wid = tid >> 6;
    if (!mask_at(mask_gt, row, mode[0])) return;   // win_fl pre-zeroed -> no claims

    float4 g = reinterpret_cast<const float4*>(gt_bboxes)[row];
    float x1a = g.x, y1a = g.y, x2a = g.z, y2a = g.w;
    float w1 = x2a - x1a, h1 = y2a - y1a + EPSC;
    float w1h1 = w1 * h1;
    float atan1 = atanf(w1 / h1);
    int lbl = (int)gt_labels[row];

    const float4* pb4 = reinterpret_cast<const float4*>(pd_bboxes + (size_t)b * A * 4);
    const float*  ps  = pd_scores + (size_t)b * A * C;
    const float2* an2 = reinterpret_cast<const float2*>(anc);
    const float4* an4 = reinterpret_cast<const float4*>(anc);

    if (tid == 0) s_p = 0;

    // Phase 1: in-box test, 4 anchors/thread/iter (vectorized), per-wave segment compaction
    int running = 0;
    const int wbase = wid * SEG;
    int aMain = A & ~1023;
    for (int base = 0; base < aMain; base += 1024) {
        int a0 = base + (tid << 2);
        int q = a0 >> 1;
        float4 p01 = an4[q];
        float4 p23 = an4[q + 1];
        bool i0 = (p01.x - x1a > EPS9) & (p01.y - y1a > EPS9) & (x2a - p01.x > EPS9) & (y2a - p01.y > EPS9);
        bool i1 = (p01.z - x1a > EPS9) & (p01.w - y1a > EPS9) & (x2a - p01.z > EPS9) & (y2a - p01.w > EPS9);
        bool i2 = (p23.x - x1a > EPS9) & (p23.y - y1a > EPS9) & (x2a - p23.x > EPS9) & (y2a - p23.y > EPS9);
        bool i3 = (p23.z - x1a > EPS9) & (p23.w - y1a > EPS9) & (x2a - p23.z > EPS9) & (y2a - p23.w > EPS9);
        unsigned long long bl; int pos;
        bl = __ballot(i0); pos = running + (int)lane_rank(bl);
        if (i0 && pos < SEG) keys[wbase + pos] = (unsigned long long)(unsigned)a0;
        running += __popcll(bl);
        bl = __ballot(i1); pos = running + (int)lane_rank(bl);
        if (i1 && pos < SEG) keys[wbase + pos] = (unsigned long long)(unsigned)(a0 + 1);
        running += __popcll(bl);
        bl = __ballot(i2); pos = running + (int)lane_rank(bl);
        if (i2 && pos < SEG) keys[wbase + pos] = (unsigned long long)(unsigned)(a0 + 2);
        running += __popcll(bl);
        bl = __ballot(i3); pos = running + (int)lane_rank(bl);
        if (i3 && pos < SEG) keys[wbase + pos] = (unsigned long long)(unsigned)(a0 + 3);
        running += __popcll(bl);
    }
    for (int a = aMain + tid; a < A; a += 256) {   // tail (divergent-exit ballot is exact)
        float2 ap = an2[a];
        bool in = (ap.x - x1a > EPS9) & (ap.y - y1a > EPS9) &
                  (x2a - ap.x > EPS9) & (y2a - ap.y > EPS9);
        unsigned long long bl = __ballot(in);
        int pos = running + (int)lane_rank(bl);
        if (in && pos < SEG) keys[wbase + pos] = (unsigned long long)(unsigned)a;
        running += __popcll(bl);
    }
    if (lane == 0) s_cnt[wid] = running;
    if constexpr (PH == 1) {
        if (lane == 0) scr[bid * 4 + wid] = running ^ (int)keys[wbase];  // keepalive
        return;
    }
    __syncthreads();
    int c0 = s_cnt[0], c1 = s_cnt[1], c2 = s_cnt[2], c3 = s_cnt[3];
    if (max(max(c0, c1), max(c2, c3)) > SEG) {     // pathological giant gt: fallback kernel
        if (tid == 0) ovf[bid] = 1;
        return;
    }
    int o1 = c0, o2 = c0 + c1, o3 = c0 + c1 + c2;
    int ntot = o3 + c3;

    // Phase 2: dense metric compute over flattened candidates
    int pcnt = 0;
    for (int gidx = tid; gidx < ntot; gidx += 256) {
        int slot = seg_slot(gidx, o1, o2, o3);
        int a = (int)(unsigned)keys[slot];
        float4 pb = pb4[a];
        float w2 = pb.z - pb.x, h2 = pb.w - pb.y + EPSC;
        float at2 = atanf(w2 / h2);
        float ovl = ciou_clip(x1a, y1a, x2a, y2a, w1h1, atan1, pb, at2);
        float sc = (lbl >= 0) ? ps[(size_t)a * C + lbl] : 0.f;
        float o2v = ovl * ovl;
        float val = sqrtf(sc) * (o2v * o2v * o2v);
        // key max-order == (val desc, idx asc); val>=0 so float bits are monotone
        keys[slot] = ((unsigned long long)__float_as_uint(val) << 32) | (unsigned)(~(unsigned)a);
        pcnt += (val > 0.f) ? 1 : 0;
    }
#pragma unroll
    for (int off = 32; off; off >>= 1) pcnt += __shfl_xor(pcnt, off);
    if (lane == 0 && pcnt) atomicAdd(&s_p, pcnt);
    __syncthreads();

    if constexpr (PH == 2) {
        if (tid == 0) scr[bid] = s_p ^ (int)keys[0];   // keepalive
        return;
    }

    if (tid >= 64) return;       // Phase 3 is single-wave, barrier-free
    int p = s_p;
    int rp = p < NTOPK ? p : NTOPK;
    int base_o = row * NTOPK;

    // Phase 3a: positive rounds (wave-synchronous; keys unique -> unique owner)
    for (int k = 0; k < rp; ++k) {
        unsigned long long lmax = 0; int lpos = -1;
        for (int gidx = lane; gidx < ntot; gidx += 64) {
            int slot = seg_slot(gidx, o1, o2, o3);
            unsigned long long kk = keys[slot];
            if (kk > lmax) { lmax = kk; lpos = slot; }
        }
        unsigned long long best = lmax;
#pragma unroll
        for (int off = 32; off; off >>= 1) {
            unsigned long long o = shfl_xor_u64(best, off);
            if (o > best) best = o;
        }
        if (lpos >= 0 && lmax == best) {
            int a = (int)(~(unsigned)(best & 0xFFFFFFFFull));
            int o = base_o + k;
            win_idx[o] = a;
            win_al[o]  = __uint_as_float((unsigned)(best >> 32));
            win_fl[o]  = 1;
            atomicAdd(&count[(size_t)b * A + a], 1);
            keys[lpos] = 0;      // re-read only by this lane next round
        }
    }

    // Phase 3b (rare: fewer than 10 positives): fill slots with smallest-index zero-val
    // anchors; in-box zero-val ones (compacted, val==0) become real zero-metric claims.
    if (rp < NTOPK) {
        int iters = (A + 63 - lane) / 64;    // #anchors a = lane + j*64 < A
        int zp = 0;                          // resume pointer over out-of-box zeros
        for (int k = rp; k < NTOPK; ++k) {
            unsigned zprop = 0xFFFFFFFFu;    // next out-of-box anchor (val==0, never a claim)
            while (zp < iters) {
                int a = lane + zp * 64;
                float2 ap = an2[a];
                bool in = (ap.x - x1a > EPS9) & (ap.y - y1a > EPS9) &
                          (x2a - ap.x > EPS9) & (y2a - ap.y > EPS9);
                if (!in) { zprop = (unsigned)a; break; }
                ++zp;
            }
            unsigned cprop = 0xFFFFFFFFu; int cpos = -1;   // unconsumed compacted zero-val
            for (int gidx = lane; gidx < ntot; gidx += 64) {
                int slot = seg_slot(gidx, o1, o2, o3);
                unsigned long long kk = keys[slot];
                if (kk != 0ull && kk < (1ull << 32)) {
                    unsigned idx2 = ~(unsigned)kk;
                    if (idx2 < cprop) { cprop = idx2; cpos = slot; }
                }
            }
            unsigned prop = zprop < cprop ? zprop : cprop;
            unsigned bm_ = prop;
#pragma unroll
            for (int off = 32; off; off >>= 1) {
                unsigned o = (unsigned)__shfl_xor((int)bm_, off);
                if (o < bm_) bm_ = o;
            }
            if (bm_ != 0xFFFFFFFFu) {
                if (cpos >= 0 && cprop == bm_ && cprop < zprop) {
                    // in-box zero-metric claim (matches reference mask_pos semantics)
                    int o = base_o + k;
                    win_idx[o] = (int)bm_; win_al[o] = 0.f; win_fl[o] = 1;
                    atomicAdd(&count[(size_t)b * A + bm_], 1);
                    keys[cpos] = 0;
                } else if (zprop == bm_ && zprop < cprop) {
                    ++zp;   // consume out-of-box zero; padding slot, no claim
                }
            }
        }
    }
}

__global__ __launch_bounds__(256) void k_topk(
    const float* __restrict__ pd_scores, const float* __restrict__ pd_bboxes,
    const float* __restrict__ anc, const float* __restrict__ gt_labels,
    const float* __restrict__ gt_bboxes, const unsigned char* __restrict__ mask_gt,
    const int* __restrict__ mode, int* count, int* win_idx, float* win_al,
    int* win_fl, int* ovf, int A, int C, int M, int B)
{
    topk_body<3>(pd_scores, pd_bboxes, anc, gt_labels, gt_bboxes, mask_gt, mode,
                 count, win_idx, win_al, win_fl, ovf, nullptr, A, C, M, B);
}

// Diagnostic ablations (write only to scr; timed via rocprof)
__global__ __launch_bounds__(256) void k_topk_p1(
    const float* __restrict__ pd_scores, const float* __restrict__ pd_bboxes,
    const float* __restrict__ anc, const float* __restrict__ gt_labels,
    const float* __restrict__ gt_bboxes, const unsigned char* __restrict__ mask_gt,
    const int* __restrict__ mode, int* scr, int A, int C, int M, int B)
{
    topk_body<1>(pd_scores, pd_bboxes, anc, gt_labels, gt_bboxes, mask_gt, mode,
                 nullptr, nullptr, nullptr, nullptr, nullptr, scr, A, C, M, B);
}

__global__ __launch_bounds__(256) void k_topk_p2(
    const float* __restrict__ pd_scores, const float* __restrict__ pd_bboxes,
    const float* __restrict__ anc, const float* __restrict__ gt_labels,
    const float* __restrict__ gt_bboxes, const unsigned char* __restrict__ mask_gt,
    const int* __restrict__ mode, int* scr, int* ovf2, int A, int C, int M, int B)
{
    topk_body<2>(pd_scores, pd_bboxes, anc, gt_labels, gt_bboxes, mask_gt, mode,
                 nullptr, nullptr, nullptr, nullptr, ovf2, scr, A, C, M, B);
}

// K2fb: exact fallback (round-3 algorithm) for blocks whose in-box count overflows a segment
__global__ __launch_bounds__(256) void k_topk_fb(
    const float* __restrict__ pd_scores, const float* __restrict__ pd_bboxes,
    const float* __restrict__ anc, const float* __restrict__ gt_labels,
    const float* __restrict__ gt_bboxes,
    const int* __restrict__ ovf,
    int* __restrict__ count, int* __restrict__ win_idx, float* __restrict__ win_al,
    int* __restrict__ win_fl,
    int A, int C, int M, int B)
{
    int bid = blockIdx.x;
    if (!ovf[bid]) return;
    int b = bid % B;                 // must match k_topk's swizzle
    int m = bid / B;
    int row = b * M + m;
    int tid = threadIdx.x;

    float4 g = reinterpret_cast<const float4*>(gt_bboxes)[row];
    float x1a = g.x, y1a = g.y, x2a = g.z, y2a = g.w;
    float w1 = x2a - x1a, h1 = y2a - y1a + EPSC;
    float w1h1 = w1 * h1;
    float atan1 = atanf(w1 / h1);
    int lbl = (int)gt_labels[row];

    const float4* pb4 = reinterpret_cast<const float4*>(pd_bboxes + (size_t)b * A * 4);
    const float*  ps  = pd_scores + (size_t)b * A * C;
    const float2* an2 = reinterpret_cast<const float2*>(anc);

    float tv[NTOPK];
    int   ti[NTOPK], tfl[NTOPK];
#pragma unroll
    for (int j = 0; j < NTOPK; ++j) { tv[j] = -1.f; ti[j] = 0x7fffffff; tfl[j] = 0; }

    for (int a = tid; a < A; a += 256) {
        float2 ap = an2[a];
        bool in = (ap.x - x1a > EPS9) & (ap.y - y1a > EPS9) &
                  (x2a - ap.x > EPS9) & (y2a - ap.y > EPS9);
        float val = 0.f;
        if (in) {
            float4 pb = pb4[a];
            float w2 = pb.z - pb.x, h2 = pb.w - pb.y + EPSC;
            float ovl = ciou_clip(x1a, y1a, x2a, y2a, w1h1, atan1, pb, atanf(w2 / h2));
            float sc = (lbl >= 0) ? ps[(size_t)a * C + lbl] : 0.f;
            float o2 = ovl * ovl;
            val = sqrtf(sc) * (o2 * o2 * o2);
        }
        if (better(val, a, tv[NTOPK - 1], ti[NTOPK - 1])) {
            tv[NTOPK - 1] = val; ti[NTOPK - 1] = a; tfl[NTOPK - 1] = in ? 1 : 0;
#pragma unroll
            for (int j = NTOPK - 1; j > 0; --j) {
                if (better(tv[j], ti[j], tv[j - 1], ti[j - 1])) {
                    float fv = tv[j]; tv[j] = tv[j - 1]; tv[j - 1] = fv;
                    int   fi = ti[j]; ti[j] = ti[j - 1]; ti[j - 1] = fi;
                    int   ff = tfl[j]; tfl[j] = tfl[j - 1]; tfl[j - 1] = ff;
                }
            }
        }
    }

    __shared__ float swv[8];
    __shared__ int   swi[8];
    int lane = tid & 63, wid = tid >> 6;
    int base_o = row * NTOPK;

    for (int k = 0; k < NTOPK; ++k) {
        float bv = -2.f; int bi = 0x7fffffff;
#pragma unroll
        for (int j = 0; j < NTOPK; ++j)
            if (better(tv[j], ti[j], bv, bi)) { bv = tv[j]; bi = ti[j]; }
#pragma unroll
        for (int off = 32; off > 0; off >>= 1) {
            float ov = __shfl_xor(bv, off);
            int   oi = __shfl_xor(bi, off);
            if (better(ov, oi, bv, bi)) { bv = ov; bi = oi; }
        }
        if (lane == 0) { swv[wid] = bv; swi[wid] = bi; }
        __syncthreads();
        if (tid == 0) {
            float gv = swv[0]; int gi = swi[0];
            for (int w = 1; w < 4; ++w)
                if (better(swv[w], swi[w], gv, gi)) { gv = swv[w]; gi = swi[w]; }
            swv[7] = gv; swi[7] = gi;
        }
        __syncthreads();
        int gbi = swi[7];
#pragma unroll
        for (int j = 0; j < NTOPK; ++j) {
            if (ti[j] == gbi) {
                int o = base_o + k;
                win_idx[o] = gbi; win_al[o] = tv[j]; win_fl[o] = tfl[j];
                if (tfl[j]) atomicAdd(&count[(size_t)b * A + gbi], 1);
                tv[j] = -2.f; ti[j] = 0x7fffffff;
            }
        }
        __syncthreads();
    }
}

// K3: claim resolution + fused pos_al/pos_ov atomicMax. Winner CIoU recomputed here
// (same formula as phase 2) instead of being stored per-candidate.
__global__ void k_resolve(
    const float* __restrict__ pd_scores, const float* __restrict__ pd_bboxes,
    const float* __restrict__ anc, const float* __restrict__ gt_labels,
    const float* __restrict__ gt_bboxes, const unsigned char* __restrict__ mask_gt,
    const int* __restrict__ mode,
    const int* __restrict__ count, const int* __restrict__ win_idx,
    const float* __restrict__ win_al, const int* __restrict__ win_fl,
    int* __restrict__ claim_m, float* __restrict__ claim_al,
    float* __restrict__ pos_al, float* __restrict__ pos_ov,
    int A, int C, int M, int total)
{
    int t = blockIdx.x * 256 + threadIdx.x;
    if (t >= total) return;
    int bm = t / NTOPK;
    int b = bm / M, m = bm % M;
    if (!win_fl[t]) return;
    int a = win_idx[t];
    size_t ba = (size_t)b * A + a;
    int cnt = count[ba];
    float al, ov; int mm_out;
    if (cnt == 1) {
        mm_out = m; al = win_al[t];
        float4 gg = reinterpret_cast<const float4*>(gt_bboxes)[b * M + m];
        float w1 = gg.z - gg.x, h1 = gg.w - gg.y + EPSC;
        float4 pb = reinterpret_cast<const float4*>(pd_bboxes)[ba];
        float w2 = pb.z - pb.x, h2p = pb.w - pb.y + EPSC;
        ov = ciou_clip(gg.x, gg.y, gg.z, gg.w, w1 * h1, atanf(w1 / h1), pb, atanf(w2 / h2p));
    } else {
        // conflicted: argmax_m of valid-masked overlaps (first-max tie; identical-value
        // writes among claimants are benign)
        int wide = mode[0];
        float4 pb = reinterpret_cast<const float4*>(pd_bboxes)[ba];
        float2 ap = reinterpret_cast<const float2*>(anc)[a];
        float w2 = pb.z - pb.x, h2p = pb.w - pb.y + EPSC;
        float at2 = atanf(w2 / h2p);
        float best_ov = -1.f; int best_m = 0, best_valid = 0;
        for (int mm = 0; mm < M; ++mm) {
            float4 gg = reinterpret_cast<const float4*>(gt_bboxes)[b * M + mm];
            bool in = (ap.x - gg.x > EPS9) && (ap.y - gg.y > EPS9) &&
                      (gg.z - ap.x > EPS9) && (gg.w - ap.y > EPS9);
            bool valid = in && mask_at(mask_gt, b * M + mm, wide);
            float ovv = 0.f;
            if (valid) {
                float w1 = gg.z - gg.x, h1 = gg.w - gg.y + EPSC;
                ovv = ciou_clip(gg.x, gg.y, gg.z, gg.w, w1 * h1, atanf(w1 / h1), pb, at2);
            }
            if (ovv > best_ov) { best_ov = ovv; best_m = mm; best_valid = valid ? 1 : 0; }
        }
        int lb = (int)gt_labels[b * M + best_m];
        float sc = (best_valid && lb >= 0) ? pd_scores[ba * C + lb] : 0.f;
        float o2 = best_ov * best_ov;
        mm_out = best_m; al = sqrtf(sc) * (o2 * o2 * o2); ov = best_ov;
    }
    claim_m[ba]  = mm_out;
    claim_al[ba] = al;
    atomicMax((unsigned int*)&pos_al[b * M + mm_out], __float_as_uint(al));
    atomicMax((unsigned int*)&pos_ov[b * M + mm_out], __float_as_uint(ov));
}

// K5b: bboxes + fg + per-anchor (norm, label)
__global__ void k_fin1(const int* __restrict__ count, const int* __restrict__ claim_m,
                       const float* __restrict__ claim_al,
                       const float* __restrict__ pos_al, const float* __restrict__ pos_ov,
                       const float* __restrict__ gt_labels, const float* __restrict__ gt_bboxes,
                       float* __restrict__ out_bb, float* __restrict__ out_fg,
                       float* __restrict__ normv, int* __restrict__ lblv,
                       int A, int M, int BA) {
    int ba = blockIdx.x * 256 + threadIdx.x;
    if (ba >= BA) return;
    int b = ba / A;
    int cnt = count[ba];
    int m = claim_m[ba];                       // 0 for background (memset)
    float4 g = reinterpret_cast<const float4*>(gt_bboxes)[b * M + m];
    reinterpret_cast<float4*>(out_bb)[ba] = g;
    float nv = 0.f; int lb = -1;
    if (cnt > 0) {
        lb = max((int)gt_labels[b * M + m], 0);
        nv = claim_al[ba] * pos_ov[b * M + m] / (pos_al[b * M + m] + EPS9);
    }
    out_fg[ba] = (cnt > 0) ? 1.f : 0.f;
    normv[ba] = nv; lblv[ba] = lb;
}

// K5a: target_scores, float4-vectorized over classes
__global__ void k_scores(const float* __restrict__ normv, const int* __restrict__ lblv,
                         float* __restrict__ out_ts, int C4, int total4) {
    int i = blockIdx.x * 256 + threadIdx.x;
    if (i >= total4) return;
    int ba = i / C4;
    int c0 = (i - ba * C4) * 4;
    float nv = normv[ba];
    int lb = lblv[ba];
    float4 o;
    o.x = (c0     == lb) ? nv : 0.f;
    o.y = (c0 + 1 == lb) ? nv : 0.f;
    o.z = (c0 + 2 == lb) ? nv : 0.f;
    o.w = (c0 + 3 == lb) ? nv : 0.f;
    reinterpret_cast<float4*>(out_ts)[i] = o;
}

extern "C" void kernel_launch(void* const* d_in, const int* in_sizes, int n_in,
                              void* d_out, int out_size, void* d_ws, size_t ws_size,
                              hipStream_t stream) {
    const float* pd_scores = (const float*)d_in[0];
    const float* pd_bboxes = (const float*)d_in[1];
    const float* anc       = (const float*)d_in[2];
    const float* gt_labels = (const float*)d_in[3];
    const float* gt_bboxes = (const float*)d_in[4];
    const unsigned char* mask_gt = (const unsigned char*)d_in[5];

    int A  = in_sizes[2] / 2;
    int BA = in_sizes[1] / 4;
    int B  = BA / A;
    int C  = in_sizes[0] / BA;
    int M  = in_sizes[3] / B;
    int BM = B * M;

    // workspace carve (256B-aligned bumps; zeroed span is contiguous)
    char* w = (char*)d_ws;
    auto alloc = [&](size_t bytes) { char* p = w; w += ((bytes + 255) / 256) * 256; return p; };
    int*   mode     = (int*)  alloc(256);
    char*  zero_beg = w;
    int*   count    = (int*)  alloc((size_t)BA * 4);
    int*   claim_m  = (int*)  alloc((size_t)BA * 4);
    float* claim_al = (float*)alloc((size_t)BA * 4);
    float* pos_al   = (float*)alloc((size_t)BM * 4);
    float* pos_ov   = (float*)alloc((size_t)BM * 4);
    int*   win_fl   = (int*)  alloc((size_t)BM * NTOPK * 4);
    int*   ovf      = (int*)  alloc((size_t)BM * 4);
    char*  zero_end = w;
    int*   win_idx  = (int*)  alloc((size_t)BM * NTOPK * 4);
    float* win_al   = (float*)alloc((size_t)BM * NTOPK * 4);
    float* normv    = (float*)alloc((size_t)BA * 4);
    int*   lblv     = (int*)  alloc((size_t)BA * 4);
    int*   scrA     = (int*)  alloc((size_t)BM * 4 * 4);   // ablation keepalives
    int*   scrB     = (int*)  alloc((size_t)BM * 4);
    int*   ovf2     = (int*)  alloc((size_t)BM * 4);

    float* out_bb = (float*)d_out;
    float* out_ts = out_bb + (size_t)BA * 4;
    float* out_fg = out_ts + (size_t)BA * C;

    hipMemsetAsync(zero_beg, 0, (size_t)(zero_end - zero_beg), stream);

    int gBA = (BA + 255) / 256;
    k_detect<<<1, 256, 0, stream>>>(mask_gt, BM, mode);
    k_topk<<<BM, 256, 0, stream>>>(pd_scores, pd_bboxes, anc, gt_labels, gt_bboxes, mask_gt,
                                   mode, count, win_idx, win_al, win_fl, ovf, A, C, M, B);
    k_topk_fb<<<BM, 256, 0, stream>>>(pd_scores, pd_bboxes, anc, gt_labels, gt_bboxes,
                                      ovf, count, win_idx, win_al, win_fl, A, C, M, B);
    int nclaims = BM * NTOPK;
    k_resolve<<<(nclaims + 255) / 256, 256, 0, stream>>>(
        pd_scores, pd_bboxes, anc, gt_labels, gt_bboxes, mask_gt, mode,
        count, win_idx, win_al, win_fl, claim_m, claim_al, pos_al, pos_ov, A, C, M, nclaims);
    k_fin1<<<gBA, 256, 0, stream>>>(count, claim_m, claim_al, pos_al, pos_ov,
                                    gt_labels, gt_bboxes, out_bb, out_fg, normv, lblv, A, M, BA);
    int C4 = C / 4;
    int total4 = BA * C4;
    k_scores<<<(total4 + 255) / 256, 256, 0, stream>>>(normv, lblv, out_ts, C4, total4);

    // Diagnostic ablations (scratch-only; read via rocprof dispatch timings)
    k_topk_p1<<<BM, 256, 0, stream>>>(pd_scores, pd_bboxes, anc, gt_labels, gt_bboxes, mask_gt,
                                      mode, scrA, A, C, M, B);
    k_topk_p2<<<BM, 256, 0, stream>>>(pd_scores, pd_bboxes, anc, gt_labels, gt_bboxes, mask_gt,
                                      mode, scrB, ovf2, A, C, M, B);
}

// Round 8
// 91.016 us; speedup vs baseline: 1.5167x; 1.5167x over previous
//
#include <hip/hip_runtime.h>
#include <cstdint>
#include <cstddef>

#define EPSC 1e-7f
#define EPS9 1e-9f
#define K4PI2 0.40528473456935108577f
#define NTOPK 10
#define SEG 448              // per-wave per-gt LDS segment (8 segs = 28 KB)

__device__ __forceinline__ bool better(float v1, int i1, float v2, int i2) {
    return (v1 > v2) || ((v1 == v2) && (i1 < i2));
}

__device__ __forceinline__ bool mask_at(const unsigned char* mb, int i, int wide) {
    if (wide) return reinterpret_cast<const unsigned int*>(mb)[i] != 0u;
    return mb[i] != 0;
}

__device__ __forceinline__ unsigned long long shfl_xor_u64(unsigned long long v, int off) {
    int lo = __shfl_xor((int)(unsigned)(v & 0xFFFFFFFFull), off);
    int hi = __shfl_xor((int)(unsigned)(v >> 32), off);
    return ((unsigned long long)(unsigned)hi << 32) | (unsigned)lo;
}

__device__ __forceinline__ unsigned lane_rank(unsigned long long ball) {
    return __builtin_amdgcn_mbcnt_hi((unsigned)(ball >> 32),
           __builtin_amdgcn_mbcnt_lo((unsigned)(ball & 0xFFFFFFFFull), 0u));
}

// flattened candidate index g -> slot within a 4-segment region (branchless)
__device__ __forceinline__ int seg_slot(int g, int o1, int o2, int o3) {
    int w = (g >= o1) + (g >= o2) + (g >= o3);
    int off = (w == 0) ? 0 : (w == 1 ? o1 : (w == 2 ? o2 : o3));
    return w * SEG + (g - off);
}

__device__ __forceinline__ float ciou_clip(float x1a, float y1a, float x2a, float y2a,
                                           float w1h1, float atan1,
                                           float4 pb, float at2) {
    float w2 = pb.z - pb.x, h2 = pb.w - pb.y + EPSC;
    float iw = fmaxf(fminf(x2a, pb.z) - fmaxf(x1a, pb.x), 0.f);
    float ih = fmaxf(fminf(y2a, pb.w) - fmaxf(y1a, pb.y), 0.f);
    float inter = iw * ih;
    float uni = w1h1 + w2 * h2 - inter;
    float iou = inter / (uni + EPSC);
    float cw = fmaxf(x2a, pb.z) - fminf(x1a, pb.x);
    float ch = fmaxf(y2a, pb.w) - fminf(y1a, pb.y);
    float c2 = cw * cw + ch * ch + EPSC;
    float dx = pb.x + pb.z - x1a - x2a;
    float dy = pb.y + pb.w - y1a - y2a;
    float rho2 = (dx * dx + dy * dy) * 0.25f;
    float dat = at2 - atan1;
    float vv = K4PI2 * dat * dat;
    float aa = vv / (vv - iou + (1.f + EPSC));
    return fmaxf(iou - (rho2 / c2 + vv * aa), 0.f);
}

// K0: detect mask_gt memory layout. wide iff all n/4 leading words are {0,1,1.0f}
__global__ void k_detect(const unsigned char* __restrict__ mask, int n, int* __restrict__ mode) {
    __shared__ int bad;
    if (threadIdx.x == 0) bad = 0;
    __syncthreads();
    const unsigned int* w = reinterpret_cast<const unsigned int*>(mask);
    int nw = n >> 2;
    for (int i = threadIdx.x; i < nw; i += 256) {
        unsigned int v = w[i];
        if (v != 0u && v != 1u && v != 0x3f800000u) atomicOr(&bad, 1);
    }
    __syncthreads();
    if (threadIdx.x == 0) mode[0] = bad ? 0 : 1;
}

// K2: 2 gts per block. Shared anchor scan; per-wave-per-gt segment compaction;
// dense metric; wave0/wave1 run the two register-based tournaments concurrently.
// Order == lax.top_k (value desc, idx asc) via u64 key (val_bits<<32)|~idx.
__global__ __launch_bounds__(256) void k_topk(
    const float* __restrict__ pd_scores, const float* __restrict__ pd_bboxes,
    const float* __restrict__ anc, const float* __restrict__ gt_labels,
    const float* __restrict__ gt_bboxes, const unsigned char* __restrict__ mask_gt,
    const int* __restrict__ mode,
    int* __restrict__ count, int* __restrict__ win_idx, float* __restrict__ win_al,
    int* __restrict__ win_fl, int* __restrict__ ovf,
    int A, int C, int M, int B)
{
    __shared__ unsigned long long keys[8 * SEG];
    __shared__ int s_cnt[8];
    __shared__ int s_p[2];

    int pbid = blockIdx.x;
    int b = pbid % B;                // XCD swizzle: same-b blocks share an XCD L2
    int mp = pbid / B;
    int m0 = 2 * mp, m1 = m0 + 1;
    int row0 = b * M + m0, row1 = b * M + m1;
    int tid = threadIdx.x;
    int lane = tid & 63, wid = tid >> 6;
    int wide = mode[0];

    bool v0 = mask_at(mask_gt, row0, wide);
    bool v1 = (m1 < M) && mask_at(mask_gt, row1, wide);
    if (!v0 && !v1) return;          // win_fl pre-zeroed -> no claims

    // per-gt params (invalid gt -> +inf box: no anchor passes)
    float x1a0 = 3e38f, y1a0 = 0.f, x2a0 = 0.f, y2a0 = 0.f, w1h10 = 0.f, at10 = 0.f;
    int lbl0 = -1;
    if (v0) {
        float4 g = reinterpret_cast<const float4*>(gt_bboxes)[row0];
        x1a0 = g.x; y1a0 = g.y; x2a0 = g.z; y2a0 = g.w;
        float w1 = x2a0 - x1a0, h1 = y2a0 - y1a0 + EPSC;
        w1h10 = w1 * h1; at10 = atanf(w1 / h1);
        lbl0 = (int)gt_labels[row0];
    }
    float x1a1 = 3e38f, y1a1 = 0.f, x2a1 = 0.f, y2a1 = 0.f, w1h11 = 0.f, at11 = 0.f;
    int lbl1 = -1;
    if (v1) {
        float4 g = reinterpret_cast<const float4*>(gt_bboxes)[row1];
        x1a1 = g.x; y1a1 = g.y; x2a1 = g.z; y2a1 = g.w;
        float w1 = x2a1 - x1a1, h1 = y2a1 - y1a1 + EPSC;
        w1h11 = w1 * h1; at11 = atanf(w1 / h1);
        lbl1 = (int)gt_labels[row1];
    }

    const float4* pb4 = reinterpret_cast<const float4*>(pd_bboxes + (size_t)b * A * 4);
    const float*  ps  = pd_scores + (size_t)b * A * C;
    const float2* an2 = reinterpret_cast<const float2*>(anc);
    const float4* an4 = reinterpret_cast<const float4*>(anc);

    if (tid == 0) { s_p[0] = 0; s_p[1] = 0; }

    // Phase 1: shared scan (4 anchors/thread/iter), dual compaction
    int r0 = 0, r1 = 0;
    const int wb0 = wid * SEG, wb1 = (4 + wid) * SEG;
    int aMain = A & ~1023;
#define TEST0(px, py) ((px - x1a0 > EPS9) & (py - y1a0 > EPS9) & (x2a0 - px > EPS9) & (y2a0 - py > EPS9))
#define TEST1(px, py) ((px - x1a1 > EPS9) & (py - y1a1 > EPS9) & (x2a1 - px > EPS9) & (y2a1 - py > EPS9))
#define COMPACT(inb, rr, wb, aa)  { unsigned long long bl = __ballot(inb); \
        int pos = rr + (int)lane_rank(bl); \
        if ((inb) && pos < SEG) keys[wb + pos] = (unsigned long long)(unsigned)(aa); \
        rr += __popcll(bl); }
    for (int base = 0; base < aMain; base += 1024) {
        int a0 = base + (tid << 2);
        int q = a0 >> 1;
        float4 p01 = an4[q];
        float4 p23 = an4[q + 1];
        bool t0, t1;
        t0 = TEST0(p01.x, p01.y); t1 = TEST1(p01.x, p01.y);
        COMPACT(t0, r0, wb0, a0);     COMPACT(t1, r1, wb1, a0);
        t0 = TEST0(p01.z, p01.w); t1 = TEST1(p01.z, p01.w);
        COMPACT(t0, r0, wb0, a0 + 1); COMPACT(t1, r1, wb1, a0 + 1);
        t0 = TEST0(p23.x, p23.y); t1 = TEST1(p23.x, p23.y);
        COMPACT(t0, r0, wb0, a0 + 2); COMPACT(t1, r1, wb1, a0 + 2);
        t0 = TEST0(p23.z, p23.w); t1 = TEST1(p23.z, p23.w);
        COMPACT(t0, r0, wb0, a0 + 3); COMPACT(t1, r1, wb1, a0 + 3);
    }
    for (int a = aMain + tid; a < A; a += 256) {
        float2 ap = an2[a];
        bool t0 = TEST0(ap.x, ap.y), t1 = TEST1(ap.x, ap.y);
        COMPACT(t0, r0, wb0, a);
        COMPACT(t1, r1, wb1, a);
    }
    if (lane == 0) { s_cnt[wid] = r0; s_cnt[4 + wid] = r1; }
    __syncthreads();

    int c00 = s_cnt[0], c01 = s_cnt[1], c02 = s_cnt[2], c03 = s_cnt[3];
    int c10 = s_cnt[4], c11 = s_cnt[5], c12 = s_cnt[6], c13 = s_cnt[7];
    int mx = max(max(max(c00, c01), max(c02, c03)), max(max(c10, c11), max(c12, c13)));
    if (mx > SEG) {                  // pathological giant gt: exact fallback handles the pair
        if (tid == 0) { if (v0) ovf[row0] = 1; if (v1) ovf[row1] = 1; }
        return;
    }
    int o01 = c00, o02 = c00 + c01, o03 = c00 + c01 + c02; int n0 = o03 + c03;
    int o11 = c10, o12 = c10 + c11, o13 = c10 + c11 + c12; int n1 = o13 + c13;
    int nsum = n0 + n1;

    // Phase 2: dense metric over concatenated candidates (gt0 then gt1)
    int pc0 = 0, pc1 = 0;
    for (int cidx = tid; cidx < nsum; cidx += 256) {
        bool g1 = cidx >= n0;
        int li = cidx - (g1 ? n0 : 0);
        int slot = (g1 ? 4 * SEG : 0) +
                   seg_slot(li, g1 ? o11 : o01, g1 ? o12 : o02, g1 ? o13 : o03);
        int a = (int)(unsigned)keys[slot];
        float4 pb = pb4[a];
        float x1a = g1 ? x1a1 : x1a0, y1a = g1 ? y1a1 : y1a0;
        float x2a = g1 ? x2a1 : x2a0, y2a = g1 ? y2a1 : y2a0;
        float w1h1 = g1 ? w1h11 : w1h10, at1 = g1 ? at11 : at10;
        int lbl = g1 ? lbl1 : lbl0;
        float w2 = pb.z - pb.x, h2 = pb.w - pb.y + EPSC;
        float at2 = atanf(w2 / h2);
        float ovl = ciou_clip(x1a, y1a, x2a, y2a, w1h1, at1, pb, at2);
        float sc = (lbl >= 0) ? ps[(size_t)a * C + lbl] : 0.f;
        float o2v = ovl * ovl;
        float val = sqrtf(sc) * (o2v * o2v * o2v);
        keys[slot] = ((unsigned long long)__float_as_uint(val) << 32) | (unsigned)(~(unsigned)a);
        bool pos = val > 0.f;
        pc0 += __popcll(__ballot(pos && !g1));
        pc1 += __popcll(__ballot(pos && g1));
    }
    if (lane == 0) { if (pc0) atomicAdd(&s_p[0], pc0); if (pc1) atomicAdd(&s_p[1], pc1); }
    __syncthreads();

    // Phase 3: wave 0 -> gt0, wave 1 -> gt1; register tournaments, barrier-free
    if (wid >= 2) return;
    bool myv = wid ? v1 : v0;
    if (!myv) return;
    int g = wid;
    int gbase = g ? 4 * SEG : 0;
    int ntot = g ? n1 : n0;
    int so1 = g ? o11 : o01, so2 = g ? o12 : o02, so3 = g ? o13 : o03;
    float x1a = g ? x1a1 : x1a0, y1a = g ? y1a1 : y1a0;
    float x2a = g ? x2a1 : x2a0, y2a = g ? y2a1 : y2a0;
    int base_o = (g ? row1 : row0) * NTOPK;
    size_t bA = (size_t)b * A;
    int p = s_p[g];
    int rp = p < NTOPK ? p : NTOPK;

    // single LDS pass -> per-lane 10-deep sorted u64 registers (lossless, see notes)
    unsigned long long tv[NTOPK];
#pragma unroll
    for (int j = 0; j < NTOPK; ++j) tv[j] = 0;
    for (int gidx = lane; gidx < ntot; gidx += 64) {
        unsigned long long kk = keys[gbase + seg_slot(gidx, so1, so2, so3)];
        if (kk > tv[NTOPK - 1]) {
            tv[NTOPK - 1] = kk;
#pragma unroll
            for (int j = NTOPK - 1; j > 0; --j)
                if (tv[j] > tv[j - 1]) { unsigned long long t = tv[j]; tv[j] = tv[j - 1]; tv[j - 1] = t; }
        }
    }

    // 3a: positive rounds — register head + wave-max butterfly, winner pops
    for (int k = 0; k < rp; ++k) {
        unsigned long long head = tv[0];
        unsigned long long best = head;
#pragma unroll
        for (int off = 32; off; off >>= 1) {
            unsigned long long o = shfl_xor_u64(best, off);
            if (o > best) best = o;
        }
        if (head == best && head != 0ull) {   // unique owner (keys unique)
            int a = (int)(~(unsigned)(best & 0xFFFFFFFFull));
            int o = base_o + k;
            win_idx[o] = a;
            win_al[o]  = __uint_as_float((unsigned)(best >> 32));
            win_fl[o]  = 1;
            atomicAdd(&count[bA + a], 1);
#pragma unroll
            for (int j = 0; j < NTOPK - 1; ++j) tv[j] = tv[j + 1];
            tv[NTOPK - 1] = 0;
        }
    }

    // 3b (rare: p < 10): fill with smallest-index zero-val anchors; in-box zero-vals
    // (still in regs — key=~idx keeps smallest indices) become real zero-metric claims.
    if (rp < NTOPK) {
        int iters = (A + 63 - lane) / 64;
        int zp = 0;
        for (int k = rp; k < NTOPK; ++k) {
            unsigned zprop = 0xFFFFFFFFu;          // next out-of-box anchor (no claim)
            while (zp < iters) {
                int a = lane + zp * 64;
                float2 ap = an2[a];
                bool in = (ap.x - x1a > EPS9) & (ap.y - y1a > EPS9) &
                          (x2a - ap.x > EPS9) & (y2a - ap.y > EPS9);
                if (!in) { zprop = (unsigned)a; break; }
                ++zp;
            }
            unsigned cprop = 0xFFFFFFFFu;          // unconsumed in-box zero-val (regs)
#pragma unroll
            for (int j = 0; j < NTOPK; ++j) {
                unsigned long long kk = tv[j];
                if (kk != 0ull && kk < (1ull << 32)) {
                    unsigned idx2 = ~(unsigned)kk;
                    if (idx2 < cprop) cprop = idx2;
                }
            }
            unsigned prop = zprop < cprop ? zprop : cprop;
            unsigned bm_ = prop;
#pragma unroll
            for (int off = 32; off; off >>= 1) {
                unsigned o = (unsigned)__shfl_xor((int)bm_, off);
                if (o < bm_) bm_ = o;
            }
            if (bm_ != 0xFFFFFFFFu) {
                if (cprop == bm_ && cprop < zprop) {
                    int o = base_o + k;
                    win_idx[o] = (int)bm_; win_al[o] = 0.f; win_fl[o] = 1;
                    atomicAdd(&count[bA + bm_], 1);
                    unsigned long long wkk = (unsigned long long)(unsigned)(~bm_);
#pragma unroll
                    for (int j = 0; j < NTOPK; ++j) if (tv[j] == wkk) tv[j] = 0;
                } else if (zprop == bm_ && zprop < cprop) {
                    ++zp;
                }
            }
        }
    }
#undef TEST0
#undef TEST1
#undef COMPACT
}

// K2fb: exact fallback (round-3 algorithm) for rows flagged by segment overflow
__global__ __launch_bounds__(256) void k_topk_fb(
    const float* __restrict__ pd_scores, const float* __restrict__ pd_bboxes,
    const float* __restrict__ anc, const float* __restrict__ gt_labels,
    const float* __restrict__ gt_bboxes,
    const int* __restrict__ ovf,
    int* __restrict__ count, int* __restrict__ win_idx, float* __restrict__ win_al,
    int* __restrict__ win_fl,
    int A, int C, int M)
{
    int row = blockIdx.x;
    if (!ovf[row]) return;
    int b = row / M;
    int tid = threadIdx.x;

    float4 g = reinterpret_cast<const float4*>(gt_bboxes)[row];
    float x1a = g.x, y1a = g.y, x2a = g.z, y2a = g.w;
    float w1 = x2a - x1a, h1 = y2a - y1a + EPSC;
    float w1h1 = w1 * h1;
    float atan1 = atanf(w1 / h1);
    int lbl = (int)gt_labels[row];

    const float4* pb4 = reinterpret_cast<const float4*>(pd_bboxes + (size_t)b * A * 4);
    const float*  ps  = pd_scores + (size_t)b * A * C;
    const float2* an2 = reinterpret_cast<const float2*>(anc);

    float tv[NTOPK];
    int   ti[NTOPK], tfl[NTOPK];
#pragma unroll
    for (int j = 0; j < NTOPK; ++j) { tv[j] = -1.f; ti[j] = 0x7fffffff; tfl[j] = 0; }

    for (int a = tid; a < A; a += 256) {
        float2 ap = an2[a];
        bool in = (ap.x - x1a > EPS9) & (ap.y - y1a > EPS9) &
                  (x2a - ap.x > EPS9) & (y2a - ap.y > EPS9);
        float val = 0.f;
        if (in) {
            float4 pb = pb4[a];
            float w2 = pb.z - pb.x, h2 = pb.w - pb.y + EPSC;
            float ovl = ciou_clip(x1a, y1a, x2a, y2a, w1h1, atan1, pb, atanf(w2 / h2));
            float sc = (lbl >= 0) ? ps[(size_t)a * C + lbl] : 0.f;
            float o2 = ovl * ovl;
            val = sqrtf(sc) * (o2 * o2 * o2);
        }
        if (better(val, a, tv[NTOPK - 1], ti[NTOPK - 1])) {
            tv[NTOPK - 1] = val; ti[NTOPK - 1] = a; tfl[NTOPK - 1] = in ? 1 : 0;
#pragma unroll
            for (int j = NTOPK - 1; j > 0; --j) {
                if (better(tv[j], ti[j], tv[j - 1], ti[j - 1])) {
                    float fv = tv[j]; tv[j] = tv[j - 1]; tv[j - 1] = fv;
                    int   fi = ti[j]; ti[j] = ti[j - 1]; ti[j - 1] = fi;
                    int   ff = tfl[j]; tfl[j] = tfl[j - 1]; tfl[j - 1] = ff;
                }
            }
        }
    }

    __shared__ float swv[8];
    __shared__ int   swi[8];
    int lane = tid & 63, wid = tid >> 6;
    int base_o = row * NTOPK;

    for (int k = 0; k < NTOPK; ++k) {
        float bv = -2.f; int bi = 0x7fffffff;
#pragma unroll
        for (int j = 0; j < NTOPK; ++j)
            if (better(tv[j], ti[j], bv, bi)) { bv = tv[j]; bi = ti[j]; }
#pragma unroll
        for (int off = 32; off > 0; off >>= 1) {
            float ov = __shfl_xor(bv, off);
            int   oi = __shfl_xor(bi, off);
            if (better(ov, oi, bv, bi)) { bv = ov; bi = oi; }
        }
        if (lane == 0) { swv[wid] = bv; swi[wid] = bi; }
        __syncthreads();
        if (tid == 0) {
            float gv = swv[0]; int gi = swi[0];
            for (int w = 1; w < 4; ++w)
                if (better(swv[w], swi[w], gv, gi)) { gv = swv[w]; gi = swi[w]; }
            swv[7] = gv; swi[7] = gi;
        }
        __syncthreads();
        int gbi = swi[7];
#pragma unroll
        for (int j = 0; j < NTOPK; ++j) {
            if (ti[j] == gbi) {
                int o = base_o + k;
                win_idx[o] = gbi; win_al[o] = tv[j]; win_fl[o] = tfl[j];
                if (tfl[j]) atomicAdd(&count[(size_t)b * A + gbi], 1);
                tv[j] = -2.f; ti[j] = 0x7fffffff;
            }
        }
        __syncthreads();
    }
}

// K3: claim resolution + fused pos_al/pos_ov atomicMax (winner CIoU recomputed)
__global__ void k_resolve(
    const float* __restrict__ pd_scores, const float* __restrict__ pd_bboxes,
    const float* __restrict__ anc, const float* __restrict__ gt_labels,
    const float* __restrict__ gt_bboxes, const unsigned char* __restrict__ mask_gt,
    const int* __restrict__ mode,
    const int* __restrict__ count, const int* __restrict__ win_idx,
    const float* __restrict__ win_al, const int* __restrict__ win_fl,
    int* __restrict__ claim_m, float* __restrict__ claim_al,
    float* __restrict__ pos_al, float* __restrict__ pos_ov,
    int A, int C, int M, int total)
{
    int t = blockIdx.x * 256 + threadIdx.x;
    if (t >= total) return;
    int bm = t / NTOPK;
    int b = bm / M, m = bm % M;
    if (!win_fl[t]) return;
    int a = win_idx[t];
    size_t ba = (size_t)b * A + a;
    int cnt = count[ba];
    float al, ov; int mm_out;
    if (cnt == 1) {
        mm_out = m; al = win_al[t];
        float4 gg = reinterpret_cast<const float4*>(gt_bboxes)[b * M + m];
        float w1 = gg.z - gg.x, h1 = gg.w - gg.y + EPSC;
        float4 pb = reinterpret_cast<const float4*>(pd_bboxes)[ba];
        float w2 = pb.z - pb.x, h2p = pb.w - pb.y + EPSC;
        ov = ciou_clip(gg.x, gg.y, gg.z, gg.w, w1 * h1, atanf(w1 / h1), pb, atanf(w2 / h2p));
    } else {
        int wide = mode[0];
        float4 pb = reinterpret_cast<const float4*>(pd_bboxes)[ba];
        float2 ap = reinterpret_cast<const float2*>(anc)[a];
        float w2 = pb.z - pb.x, h2p = pb.w - pb.y + EPSC;
        float at2 = atanf(w2 / h2p);
        float best_ov = -1.f; int best_m = 0, best_valid = 0;
        for (int mm = 0; mm < M; ++mm) {
            float4 gg = reinterpret_cast<const float4*>(gt_bboxes)[b * M + mm];
            bool in = (ap.x - gg.x > EPS9) && (ap.y - gg.y > EPS9) &&
                      (gg.z - ap.x > EPS9) && (gg.w - ap.y > EPS9);
            bool valid = in && mask_at(mask_gt, b * M + mm, wide);
            float ovv = 0.f;
            if (valid) {
                float w1 = gg.z - gg.x, h1 = gg.w - gg.y + EPSC;
                ovv = ciou_clip(gg.x, gg.y, gg.z, gg.w, w1 * h1, atanf(w1 / h1), pb, at2);
            }
            if (ovv > best_ov) { best_ov = ovv; best_m = mm; best_valid = valid ? 1 : 0; }
        }
        int lb = (int)gt_labels[b * M + best_m];
        float sc = (best_valid && lb >= 0) ? pd_scores[ba * C + lb] : 0.f;
        float o2 = best_ov * best_ov;
        mm_out = best_m; al = sqrtf(sc) * (o2 * o2 * o2); ov = best_ov;
    }
    claim_m[ba]  = mm_out;
    claim_al[ba] = al;
    atomicMax((unsigned int*)&pos_al[b * M + mm_out], __float_as_uint(al));
    atomicMax((unsigned int*)&pos_ov[b * M + mm_out], __float_as_uint(ov));
}

// K4: fused finalize — per-anchor (bb, fg, nv, lb) then coalesced score writes
__global__ __launch_bounds__(256) void k_final(
    const int* __restrict__ count, const int* __restrict__ claim_m,
    const float* __restrict__ claim_al,
    const float* __restrict__ pos_al, const float* __restrict__ pos_ov,
    const float* __restrict__ gt_labels, const float* __restrict__ gt_bboxes,
    float* __restrict__ out_bb, float* __restrict__ out_ts, float* __restrict__ out_fg,
    int A, int M, int C4, int BA)
{
    __shared__ float s_nv[256];
    __shared__ int   s_lb[256];
    int base_ba = blockIdx.x * 256;
    int tid = threadIdx.x;
    int ba = base_ba + tid;
    if (ba < BA) {
        int b = ba / A;
        int cnt = count[ba];
        int m = claim_m[ba];                   // 0 for background (memset)
        float4 g = reinterpret_cast<const float4*>(gt_bboxes)[b * M + m];
        reinterpret_cast<float4*>(out_bb)[ba] = g;
        float nv = 0.f; int lb = -1;
        if (cnt > 0) {
            lb = max((int)gt_labels[b * M + m], 0);
            nv = claim_al[ba] * pos_ov[b * M + m] / (pos_al[b * M + m] + EPS9);
        }
        out_fg[ba] = (cnt > 0) ? 1.f : 0.f;
        s_nv[tid] = nv; s_lb[tid] = lb;
    } else { s_nv[tid] = 0.f; s_lb[tid] = -1; }
    __syncthreads();
    float4* ts4 = reinterpret_cast<float4*>(out_ts);
    size_t fbase = (size_t)base_ba * C4;
    for (int j = 0; j < C4; ++j) {
        int fl = j * 256 + tid;                // consecutive tid -> consecutive float4s
        int la = fl / 20;                      // C4 == 20 for this problem; general below
        int ch;
        if (C4 == 20) { la = fl / 20; ch = fl - la * 20; }
        else          { la = fl / C4; ch = fl - la * C4; }
        int ba2 = base_ba + la;
        if (ba2 < BA) {
            float nv = s_nv[la];
            int lb = s_lb[la];
            int c0 = ch * 4;
            float4 o;
            o.x = (c0     == lb) ? nv : 0.f;
            o.y = (c0 + 1 == lb) ? nv : 0.f;
            o.z = (c0 + 2 == lb) ? nv : 0.f;
            o.w = (c0 + 3 == lb) ? nv : 0.f;
            ts4[fbase + fl] = o;
        }
    }
}

extern "C" void kernel_launch(void* const* d_in, const int* in_sizes, int n_in,
                              void* d_out, int out_size, void* d_ws, size_t ws_size,
                              hipStream_t stream) {
    const float* pd_scores = (const float*)d_in[0];
    const float* pd_bboxes = (const float*)d_in[1];
    const float* anc       = (const float*)d_in[2];
    const float* gt_labels = (const float*)d_in[3];
    const float* gt_bboxes = (const float*)d_in[4];
    const unsigned char* mask_gt = (const unsigned char*)d_in[5];

    int A  = in_sizes[2] / 2;
    int BA = in_sizes[1] / 4;
    int B  = BA / A;
    int C  = in_sizes[0] / BA;
    int M  = in_sizes[3] / B;
    int BM = B * M;

    // workspace carve (256B-aligned bumps; zeroed span is contiguous)
    char* w = (char*)d_ws;
    auto alloc = [&](size_t bytes) { char* p = w; w += ((bytes + 255) / 256) * 256; return p; };
    int*   mode     = (int*)  alloc(256);
    char*  zero_beg = w;
    int*   count    = (int*)  alloc((size_t)BA * 4);
    int*   claim_m  = (int*)  alloc((size_t)BA * 4);
    float* pos_al   = (float*)alloc((size_t)BM * 4);
    float* pos_ov   = (float*)alloc((size_t)BM * 4);
    int*   win_fl   = (int*)  alloc((size_t)BM * NTOPK * 4);
    int*   ovf      = (int*)  alloc((size_t)BM * 4);
    char*  zero_end = w;
    float* claim_al = (float*)alloc((size_t)BA * 4);
    int*   win_idx  = (int*)  alloc((size_t)BM * NTOPK * 4);
    float* win_al   = (float*)alloc((size_t)BM * NTOPK * 4);

    float* out_bb = (float*)d_out;
    float* out_ts = out_bb + (size_t)BA * 4;
    float* out_fg = out_ts + (size_t)BA * C;

    hipMemsetAsync(zero_beg, 0, (size_t)(zero_end - zero_beg), stream);

    k_detect<<<1, 256, 0, stream>>>(mask_gt, BM, mode);
    int nPairs = B * ((M + 1) / 2);
    k_topk<<<nPairs, 256, 0, stream>>>(pd_scores, pd_bboxes, anc, gt_labels, gt_bboxes, mask_gt,
                                       mode, count, win_idx, win_al, win_fl, ovf, A, C, M, B);
    k_topk_fb<<<BM, 256, 0, stream>>>(pd_scores, pd_bboxes, anc, gt_labels, gt_bboxes,
                                      ovf, count, win_idx, win_al, win_fl, A, C, M);
    int nclaims = BM * NTOPK;
    k_resolve<<<(nclaims + 255) / 256, 256, 0, stream>>>(
        pd_scores, pd_bboxes, anc, gt_labels, gt_bboxes, mask_gt, mode,
        count, win_idx, win_al, win_fl, claim_m, claim_al, pos_al, pos_ov, A, C, M, nclaims);
    int C4 = C / 4;
    int gBA = (BA + 255) / 256;
    k_final<<<gBA, 256, 0, stream>>>(count, claim_m, claim_al, pos_al, pos_ov,
                                     gt_labels, gt_bboxes, out_bb, out_ts, out_fg, A, M, C4, BA);
}